// Round 9
// baseline (53.822 us; speedup 1.0000x reference)
//
#include <hip/hip_runtime.h>
#include <hip/hip_bf16.h>

// Problem constants (from reference)
#define BB 4
#define T1 16
#define T2 32
#define TPn 8
#define Hh 16
#define Kk 64
#define Mm 2049   // 2*H*K + 1

typedef float  floatx4 __attribute__((ext_vector_type(4)));
typedef int    intx4   __attribute__((ext_vector_type(4)));

// Output: ct_val [B,T1,T2,M,TP] fp32
// ct_val = (dis_sum[b,t1,t2] - dis_sta[b,t1,t2,tp] + dis_cnc[b,t1,t2,m,tp]) / TP
// distance(c1,c2,v) = sgn(c1)*sgn(c2)*(1 - s)*v, s = table[|c1|^|c2|]
// Verified semantics (R3, absmax 3.7e-9): f32 log(x)/log(2) exact at x+1=2^k
// except k=13,15 (one ulp low => floor=k-1):
//   16*(1-s) = __clz(x+1) - 16 + (x==8191 || x==32767)
// R6 lesson: one-mask form is WRONG (accepts 0xA000). Exact comparisons only.
// R7 lesson: nontemporal stores regress (35.4 vs 30.2us). Plain stores.
// R8 lesson: block-parallelism >> per-wave store depth.
// R9: one (bt,t2) row per block, m-inner loop: zero LDS/barriers, block-uniform
// coefficients in registers, 4KB dense-linear store per block-iteration.

__device__ __forceinline__ float omss16(int x) {
    int c = __clz(x + 1) - 16;
    if (x == 8191 || x == 32767) c += 1;
    return (float)c;
}

__global__ __launch_bounds__(256)
void critigraph_kernel(const int* __restrict__ sta_loc,   // [B,T1,TP]
                       const int* __restrict__ pos_loc,   // [B,T2,TP]
                       const float* __restrict__ val_n,   // [B,T1,T2]
                       const int* __restrict__ rand_raw,  // [B*T1,H,K,TP]
                       const int* __restrict__ perm,      // [M]
                       float* __restrict__ out)           // [B,T1,T2,M,TP]
{
    const int t2  = blockIdx.x;        // 0..31
    const int bt  = blockIdx.y;        // b*T1 + t1, 0..63
    const int b   = bt >> 4;           // bt / T1
    const int tid = threadIdx.x;

    // ---- block-uniform coefficients (8 per class), fully unrolled -> regs
    const float v = val_n[bt * T2 + t2];
    int   ori8[TPn], pabs8[TPn];
    float dis8[TPn], vs8v[TPn];
    float dsum = 0.0f;
    #pragma unroll
    for (int tp = 0; tp < TPn; ++tp) {
        int sv = sta_loc[bt * TPn + tp];
        int sa = sv < 0 ? -sv : sv;
        float ssgn = (sv >= 0) ? 1.0f : -1.0f;
        int pv = pos_loc[(b * T2 + t2) * TPn + tp];
        int pa = pv < 0 ? -pv : pv;
        float psgn = (pv >= 0) ? 1.0f : -1.0f;
        float d = ssgn * psgn * (omss16(sa ^ pa) * 0.0625f) * v;
        ori8[tp]  = sa;
        pabs8[tp] = pa;
        vs8v[tp]  = psgn * v * 0.125f;
        dis8[tp]  = d;
        dsum += d;
    }

    // ---- per-thread quad select (tid&1 chooses tp 0-3 or 4-7), static idx
    const bool hi = (tid & 1);
    int   ori_t[4], pabs_t[4];
    float vs_t[4], base_t[4];
    #pragma unroll
    for (int j = 0; j < 4; ++j) {
        ori_t[j]  = hi ? ori8[4 + j]  : ori8[j];
        pabs_t[j] = hi ? pabs8[4 + j] : pabs8[j];
        vs_t[j]   = hi ? vs8v[4 + j]  : vs8v[j];
        float dj  = hi ? dis8[4 + j]  : dis8[j];
        base_t[j] = (dsum - dj) * 0.125f;
    }

    const int q4 = hi ? 4 : 0;
    const int mlane = tid >> 1;                  // 0..127
    float* rowp = out + ((long long)(bt * T2 + t2) * Mm) * TPn + q4;
    const int* rbase = rand_raw + (bt * Hh) * (Kk * TPn) + q4;

    // ---- 16 full iterations over m (branchless candidate build), + tail
    #pragma unroll 2
    for (int it = 0; it < 16; ++it) {
        const int m  = it * 128 + mlane;
        const int pm = perm[m];
        const bool isori = (pm == Hh * Kk);
        const int  r  = (pm < Hh * Kk) ? pm : pm - (Hh * Kk + 1);
        const int  rs = isori ? 0 : r;           // safe index
        const int  jj = rs >> 6;
        const int  k  = rs & 63;
        const intx4 rv = *(const intx4*)(rbase + (jj * Kk + k) * TPn);
        const int  mb   = (1 << jj) - 1;
        const int  flip = 1 << jj;
        const float ngv = (pm <= Hh * Kk) ? 0.0625f : -0.0625f;
        floatx4 o;
        #pragma unroll
        for (int j = 0; j < 4; ++j) {
            int res = (ori_t[j] ^ flip) ^ (rv[j] & mb);
            int aj  = isori ? ori_t[j] : res;
            float sg = (aj == 0) ? 0.0625f : ngv;
            float c  = omss16(aj ^ pabs_t[j]);
            o[j] = fmaf(c * sg, vs_t[j], base_t[j]);
        }
        *(floatx4*)(rowp + (long long)m * TPn) = o;
    }
    // tail: m = 2048 (perm[2048]); only threads 0,1 store
    if (tid < 2) {
        const int m  = 2048;
        const int pm = perm[m];
        const bool isori = (pm == Hh * Kk);
        const int  r  = (pm < Hh * Kk) ? pm : pm - (Hh * Kk + 1);
        const int  rs = isori ? 0 : r;
        const int  jj = rs >> 6;
        const int  k  = rs & 63;
        const intx4 rv = *(const intx4*)(rbase + (jj * Kk + k) * TPn);
        const int  mb   = (1 << jj) - 1;
        const int  flip = 1 << jj;
        const float ngv = (pm <= Hh * Kk) ? 0.0625f : -0.0625f;
        floatx4 o;
        #pragma unroll
        for (int j = 0; j < 4; ++j) {
            int res = (ori_t[j] ^ flip) ^ (rv[j] & mb);
            int aj  = isori ? ori_t[j] : res;
            float sg = (aj == 0) ? 0.0625f : ngv;
            float c  = omss16(aj ^ pabs_t[j]);
            o[j] = fmaf(c * sg, vs_t[j], base_t[j]);
        }
        *(floatx4*)(rowp + (long long)m * TPn) = o;
    }
}

extern "C" void kernel_launch(void* const* d_in, const int* in_sizes, int n_in,
                              void* d_out, int out_size, void* d_ws, size_t ws_size,
                              hipStream_t stream) {
    const int*   sta_loc  = (const int*)d_in[0];
    const int*   pos_loc  = (const int*)d_in[1];
    const float* val_n    = (const float*)d_in[2];
    const int*   rand_raw = (const int*)d_in[3];
    const int*   perm     = (const int*)d_in[4];
    float* out = (float*)d_out;

    dim3 grid(T2, BB * T1);   // (32, 64) = 2048 blocks, one output row each
    critigraph_kernel<<<grid, 256, 0, stream>>>(sta_loc, pos_loc, val_n,
                                                rand_raw, perm, out);
}

// Round 10
// 27.847 us; speedup vs baseline: 1.9328x; 1.9328x over previous
//
#include <hip/hip_runtime.h>
#include <hip/hip_bf16.h>

// Problem constants (from reference)
#define BB 4
#define T1 16
#define T2 32
#define TPn 8
#define Hh 16
#define Kk 64
#define Mm 2049   // 2*H*K + 1
#define NT2B 4    // t2 values handled per block (T2/8)

typedef float  floatx4 __attribute__((ext_vector_type(4)));
typedef int    intx4   __attribute__((ext_vector_type(4)));

// Output: ct_val [B,T1,T2,M,TP] fp32
// ct_val = (dis_sum[b,t1,t2] - dis_sta[b,t1,t2,tp] + dis_cnc[b,t1,t2,m,tp]) / TP
// distance(c1,c2,v) = sgn(c1)*sgn(c2)*(1 - s)*v, s = table[|c1|^|c2|]
// Verified semantics (R3, absmax 3.7e-9): f32 log(x)/log(2) exact at x+1=2^k
// except k=13,15 (one ulp low => floor=k-1):
//   16*(1-s) = __clz(x+1) - 16 + (x==8191 || x==32767)
// R6: one-mask form WRONG (accepts 0xA000). R7: nt stores regress.
// R8: fewer/longer blocks regress (TLP). R9: per-store gathers regress
// (amortize gather once per thread). This round: z=8 (more/shorter blocks).

__device__ __forceinline__ float omss16(int x) {
    int c = __clz(x + 1) - 16;
    if (x == 8191 || x == 32767) c += 1;
    return (float)c;
}

__global__ __launch_bounds__(256)
void critigraph_kernel(const int* __restrict__ sta_loc,   // [B,T1,TP]
                       const int* __restrict__ pos_loc,   // [B,T2,TP]
                       const float* __restrict__ val_n,   // [B,T1,T2]
                       const int* __restrict__ rand_raw,  // [B*T1,H,K,TP]
                       const int* __restrict__ perm,      // [M]
                       float* __restrict__ out)           // [B,T1,T2,M,TP]
{
    const int bt  = blockIdx.x;        // b*T1 + t1
    const int b   = bt / T1;
    const int mc  = blockIdx.y;        // m chunk of 128 (0..16)
    const int t2q = blockIdx.z;        // t2 eighth (0..7), 4 t2 each
    const int tid = threadIdx.x;

    __shared__ __align__(16) int   s_pabs[NT2B * TPn];   // |pos|
    __shared__ __align__(16) float s_vs8[NT2B * TPn];    // sgn(pos)*val/8
    __shared__ __align__(16) float s_base8[NT2B * TPn];  // (dis_sum - dis_sta)/8
    __shared__ float s_dis[NT2B * TPn];                  // dis_sta (temp)
    __shared__ float s_sum[NT2B];                        // dis_sum per t2
    __shared__ int   s_ori[TPn];                         // |sta|

    if (tid < TPn) {
        int sv = sta_loc[bt * TPn + tid];
        s_ori[tid] = sv < 0 ? -sv : sv;
    }
    if (tid < NT2B * TPn) {
        const int t2l = tid >> 3;
        const int tp  = tid & 7;
        const int t2  = t2q * NT2B + t2l;
        int pv = pos_loc[(b * T2 + t2) * TPn + tp];
        int pa = pv < 0 ? -pv : pv;
        float psgn = (pv >= 0) ? 1.0f : -1.0f;
        int sv = sta_loc[bt * TPn + tp];
        int sa = sv < 0 ? -sv : sv;
        float ssgn = (sv >= 0) ? 1.0f : -1.0f;
        float v = val_n[bt * T2 + t2];
        int x = sa ^ pa;
        s_dis[tid]  = ssgn * psgn * (omss16(x) * 0.0625f) * v;
        s_pabs[tid] = pa;
        s_vs8[tid]  = psgn * v * 0.125f;
    }
    __syncthreads();
    if (tid < NT2B) {
        const float* d = &s_dis[tid * TPn];
        float acc = 0.0f;
        #pragma unroll
        for (int tp = 0; tp < TPn; ++tp) acc += d[tp];
        s_sum[tid] = acc;
    }
    __syncthreads();
    if (tid < NT2B * TPn) {
        s_base8[tid] = (s_sum[tid >> 3] - s_dis[tid]) * 0.125f;
    }
    __syncthreads();

    const int m = mc * 128 + (tid >> 1);
    if (m >= Mm) return;
    const int q4 = (tid & 1) * 4;          // which half of the 8 tp's

    // ---- build candidate coordinate for tp in [q4, q4+4)
    int   a[4];
    float sg16[4];
    const int pm = perm[m];
    if (pm == Hh * Kk) {   // == 1024: the original coordinate
        #pragma unroll
        for (int j = 0; j < 4; ++j) { a[j] = s_ori[q4 + j]; sg16[j] = 0.0625f; }
    } else {
        const int r   = (pm < Hh * Kk) ? pm : pm - (Hh * Kk + 1);
        const float ng = (pm < Hh * Kk) ? 0.0625f : -0.0625f;
        const int jj  = r >> 6;           // r / K
        const int k   = r & 63;           // r % K
        const int mb  = (1 << jj) - 1;    // mod 2^jj
        const int flip = 1 << jj;
        const int* rr = rand_raw + ((bt * Hh + jj) * Kk + k) * TPn + q4;
        #pragma unroll
        for (int j = 0; j < 4; ++j) {
            int res = (s_ori[q4 + j] ^ flip) ^ (rr[j] & mb);
            a[j] = res;
            sg16[j] = (res == 0) ? 0.0625f : ng;  // sign(+0)=+1
        }
    }

    // ---- 4 t2 iterations; one fully-coalesced 16B store each
    // lane tid writes bytes [tid*16, tid*16+16) of each wave's 1KB span
    float* op = out + ((long long)(bt * T2 + t2q * NT2B) * Mm + m) * TPn + q4;
    #pragma unroll
    for (int t2l = 0; t2l < NT2B; ++t2l) {
        const int idx = t2l * TPn + q4;
        const intx4   pv = *(const intx4*)&s_pabs[idx];
        const floatx4 vs = *(const floatx4*)&s_vs8[idx];
        const floatx4 bs = *(const floatx4*)&s_base8[idx];
        floatx4 o;
        o.x = fmaf(omss16(a[0] ^ pv.x) * sg16[0], vs.x, bs.x);
        o.y = fmaf(omss16(a[1] ^ pv.y) * sg16[1], vs.y, bs.y);
        o.z = fmaf(omss16(a[2] ^ pv.z) * sg16[2], vs.z, bs.z);
        o.w = fmaf(omss16(a[3] ^ pv.w) * sg16[3], vs.w, bs.w);
        *(floatx4*)(op + (long long)t2l * (Mm * TPn)) = o;
    }
}

extern "C" void kernel_launch(void* const* d_in, const int* in_sizes, int n_in,
                              void* d_out, int out_size, void* d_ws, size_t ws_size,
                              hipStream_t stream) {
    const int*   sta_loc  = (const int*)d_in[0];
    const int*   pos_loc  = (const int*)d_in[1];
    const float* val_n    = (const float*)d_in[2];
    const int*   rand_raw = (const int*)d_in[3];
    const int*   perm     = (const int*)d_in[4];
    float* out = (float*)d_out;

    dim3 grid(BB * T1, (Mm + 127) / 128, 8);   // (64, 17, 8) = 8704 blocks
    critigraph_kernel<<<grid, 256, 0, stream>>>(sta_loc, pos_loc, val_n,
                                                rand_raw, perm, out);
}